// Round 7
// baseline (857.818 us; speedup 1.0000x reference)
//
#include <hip/hip_runtime.h>

typedef float    float4v __attribute__((ext_vector_type(4)));
typedef float4v  float4u __attribute__((aligned(4)));   // dword-aligned vec4 load
typedef _Float16 f16x2   __attribute__((ext_vector_type(2)));
typedef _Float16 f16x4   __attribute__((ext_vector_type(4)));
typedef _Float16 f16x8   __attribute__((ext_vector_type(8)));

#if defined(__has_builtin)
#  if __has_builtin(__builtin_amdgcn_fdot2)
#    define USE_FDOT2 1
#  else
#    define USE_FDOT2 0
#  endif
#  if __has_builtin(__builtin_amdgcn_cvt_pkrtz)
#    define USE_PKRTZ 1
#  else
#    define USE_PKRTZ 0
#  endif
#else
#  define USE_FDOT2 0
#  define USE_PKRTZ 0
#endif

__device__ __forceinline__ float fdot2f(f16x2 a, f16x2 b, float c) {
#if USE_FDOT2
    return __builtin_amdgcn_fdot2(a, b, c, false);
#else
    return fmaf((float)a[1], (float)b[1], fmaf((float)a[0], (float)b[0], c));
#endif
}
__device__ __forceinline__ f16x2 pk2(float x, float y) {
#if USE_PKRTZ
    // builtin returns __fp16 ext_vector(2); same size/layout as f16x2 -> bit_cast
    return __builtin_bit_cast(f16x2, __builtin_amdgcn_cvt_pkrtz(x, y));
#else
    return (f16x2){(_Float16)x, (_Float16)y};
#endif
}

// x1 = concat(feats_t, plf_1) (query), x2 = concat(feats_r, plf_2) (reference)
// corr[d,b,h,w] = sum_c x1[b,c,h,w] * x2pad[b,c,h+dy,w+dx], d=(dy,dx) in 13x13
// out[b,0,h,w] = sum_d softmax_d(corr) * imgpad[b,0,h+dy,w+dx]
//
// Block = 256 thr = 4 waves = one FULL row (b,h); wave cs owns a 32-channel
// slice (16 channel-pairs); lane owns 4 pixels (w0=4*lane). Staged LDS layout
// is shifted (unit = col + 6) so each lane's 16-unit window [w0-6, w0+10) is
// EXACTLY 4 x ds_read_b128 at 16B-aligned, 16B lane-stride -> contiguous
// conflict-free streaming (16B/px/cp vs 28B + 4-way conflicts before).
// Two cp-phases of 8 keep staging LDS at 34.8KB -> 61.4KB total, 2 blocks/CU.
__global__ __launch_bounds__(256, 2)
void corr_soft_warp(const float* __restrict__ feats_r,
                    const float* __restrict__ feats_t,
                    const float* __restrict__ img_r,
                    const float* __restrict__ plf_1,
                    const float* __restrict__ plf_2,
                    float* __restrict__ out)
{
    constexpr int W = 256;
    constexpr int NPIX = 256 * 256;
    // stg[cs][cpl][unit]: unit u <-> global col u-6; units 0..267 used (268..271 pad)
    __shared__ __align__(16) f16x2    stg[4][8][272];   // 34,816 B (per-phase, wave-private)
    __shared__ __align__(16) _Float16 pc2[13][4][256];  // 26,624 B [dx][slice][px]

    // XCD-aware swizzle: 1024 blocks, 8 XCDs -> 128 consecutive rows per XCD
    const int bid     = (int)blockIdx.x;
    const int logical = (bid & 7) * 128 + (bid >> 3);
    const int b = logical >> 8;                // batch 0..3
    const int h = logical & 255;               // output row

    const int tid  = (int)threadIdx.x;
    const int cs   = tid >> 6;                 // wave = channel-slice 0..3
    const int lane = tid & 63;
    const int w0   = lane << 2;                // first of my 4 pixels

    const size_t plane = (size_t)NPIX;
    // cs -> 32-ch slice: cs0:[0,32) feats, cs1:[32,64) feats, cs2:[0,32) plf, cs3:[32,64) plf
    const float* __restrict__ x1arr = ((cs < 2) ? feats_t : plf_1) + (size_t)b * 64 * plane;
    const float* __restrict__ x2arr = ((cs < 2) ? feats_r : plf_2) + (size_t)b * 64 * plane;
    const float* __restrict__ img   = img_r + (size_t)b * plane;
    const int cl0 = (cs & 1) << 5;             // 0 or 32

    // ---- prologue: my x1 (4 px x 32 ch) -> channel-paired f16x2 regs (64 VGPR) ----
    f16x2 x1r[4][16];
    {
        const float* p0 = x1arr + (size_t)cl0 * plane + (size_t)h * W + w0;  // 16B-aligned
        #pragma unroll
        for (int cp = 0; cp < 16; ++cp) {
            float4v a = *(const float4v*)(p0 + (size_t)(2 * cp) * plane);
            float4v c = *(const float4v*)(p0 + (size_t)(2 * cp + 1) * plane);
            #pragma unroll
            for (int pix = 0; pix < 4; ++pix)
                x1r[pix][cp] = pk2(a[pix], c[pix]);
        }
    }

    const int p = tid;                         // softmax pixel (0..255), no dup work
    float m = -1e30f, lsum = 0.f, acc = 0.f;

    #pragma unroll 1
    for (int dy = 0; dy < 13; ++dy) {
        const int row = h + dy - 6;
        const bool inRow = ((unsigned)row < 256u);   // block-uniform (one h/block)
        float s[13], iw[13];

        if (inRow) {
            float corr[4][13];
            #pragma unroll
            for (int pix = 0; pix < 4; ++pix)
                #pragma unroll
                for (int dx = 0; dx < 13; ++dx) corr[pix][dx] = 0.f;

            const float* rbase = x2arr + (size_t)cl0 * plane + (size_t)row * W;

            #pragma unroll
            for (int ph = 0; ph < 2; ++ph) {
                // ---- stage 8 channel-pairs x 268 units into stg[cs] (wave-private,
                //      no barrier; same-wave ds ordering via lgkmcnt) ----
                #pragma unroll
                for (int cpl = 0; cpl < 8; ++cpl) {
                    const int cp = ph * 8 + cpl;
                    const float* r0 = rbase + (size_t)(2 * cp) * plane;
                    const float* r1 = r0 + plane;
                    #pragma unroll
                    for (int xq = 0; xq < 2; ++xq) {       // main quad + edge quads
                        const int q = xq ? (64 + lane) : lane;
                        const bool active = (xq == 0) | (lane < 3);
                        if (active) {
                            const int gq = 4 * q - 6;      // first col of quad (== 2 mod 4)
                            float4v A, B;
                            if (gq >= 0 && gq <= 252) {    // fully in-bounds
                                A = *(const float4u*)(r0 + gq);   // dword-aligned vec4
                                B = *(const float4u*)(r1 + gq);
                            } else {                        // OOB / straddle: lanes 0..2 only
                                #pragma unroll
                                for (int k = 0; k < 4; ++k) {
                                    const int cc = gq + k;
                                    const bool ok = ((unsigned)cc < 256u);
                                    A[k] = ok ? r0[cc] : 0.f;
                                    B[k] = ok ? r1[cc] : 0.f;
                                }
                            }
                            f16x8 e;
                            #pragma unroll
                            for (int k = 0; k < 4; ++k) {
                                f16x2 t = pk2(A[k], B[k]);
                                e[2 * k]     = t[0];
                                e[2 * k + 1] = t[1];
                            }
                            *(f16x8*)&stg[cs][cpl][q << 2] = e;   // 16B-aligned b128 write
                        }
                    }
                }
                // ---- hot loop: window units [4l, 4l+16) = cols [w0-6, w0+10) ----
                #pragma unroll
                for (int cpl = 0; cpl < 8; ++cpl) {
                    const int cp = ph * 8 + cpl;
                    union { f16x8 v8; f16x2 v2[4]; } Q[4];
                    #pragma unroll
                    for (int mq = 0; mq < 4; ++mq)         // 4 x b128, 16B lane-stride
                        Q[mq].v8 = *(const f16x8*)&stg[cs][cpl][w0 + (mq << 2)];
                    #pragma unroll
                    for (int pix = 0; pix < 4; ++pix) {
                        const f16x2 xv = x1r[pix][cp];
                        #pragma unroll
                        for (int dx = 0; dx < 13; ++dx) {
                            const int u = pix + dx;        // 0..15, compile-time
                            corr[pix][dx] = fdot2f(xv, Q[u >> 2].v2[u & 3], corr[pix][dx]);
                        }
                    }
                }
            }
            // ---- publish partials: pc2[dx][slice][px], 13 conflict-free b64 writes ----
            #pragma unroll
            for (int dx = 0; dx < 13; ++dx) {
                f16x4 v = {(_Float16)corr[0][dx], (_Float16)corr[1][dx],
                           (_Float16)corr[2][dx], (_Float16)corr[3][dx]};
                *(f16x4*)&pc2[dx][cs][w0] = v;
            }
        }
        __syncthreads();

        if (inRow) {
            // ---- cross-slice reduce + img gather for my pixel ----
            const float* imrow = img + (size_t)row * W;
            #pragma unroll
            for (int dx = 0; dx < 13; ++dx) {
                s[dx] = ((float)pc2[dx][0][p] + (float)pc2[dx][1][p])
                      + ((float)pc2[dx][2][p] + (float)pc2[dx][3][p]);
                const int col = p + dx - 6;
                iw[dx] = ((unsigned)col < 256u) ? imrow[col] : 0.f;
            }
        } else {
            // fully padded row: corr == 0 for all 13 dx, img == 0 (participates in softmax)
            #pragma unroll
            for (int dx = 0; dx < 13; ++dx) { s[dx] = 0.f; iw[dx] = 0.f; }
        }
        __syncthreads();                       // pc2/stg reusable next dy

        // ---- online softmax update (running max / sum / weighted acc) ----
        float mloc = s[0];
        #pragma unroll
        for (int dx = 1; dx < 13; ++dx) mloc = fmaxf(mloc, s[dx]);
        const float mn = fmaxf(m, mloc);
        const float scale = __expf(m - mn);
        lsum *= scale; acc *= scale;
        #pragma unroll
        for (int dx = 0; dx < 13; ++dx) {
            const float e = __expf(s[dx] - mn);
            lsum += e;
            acc = fmaf(e, iw[dx], acc);
        }
        m = mn;
    }

    out[(size_t)b * plane + (size_t)h * W + p] = acc / lsum;
}

extern "C" void kernel_launch(void* const* d_in, const int* in_sizes, int n_in,
                              void* d_out, int out_size, void* d_ws, size_t ws_size,
                              hipStream_t stream) {
    const float* feats_r = (const float*)d_in[0];
    const float* feats_t = (const float*)d_in[1];
    const float* img_r   = (const float*)d_in[2];
    const float* plf_1   = (const float*)d_in[3];
    const float* plf_2   = (const float*)d_in[4];
    float* outp = (float*)d_out;

    corr_soft_warp<<<dim3(1024), dim3(256), 0, stream>>>(
        feats_r, feats_t, img_r, plf_1, plf_2, outp);
}